// Round 10
// baseline (84.760 us; speedup 1.0000x reference)
//
#include <hip/hip_runtime.h>
#include <math.h>

#define LL 768
#define CT 64
#define KD 192
#define OC 1024
#define TS 16
#define NST 48           // 768/16 tiles per dim
#define PCH 68           // partial line: 64 ch + z at [64], padded to 68

// 16-lane-group sum via DPP: quad_perm(xor1), quad_perm(xor2), row_ror:4,
// row_ror:8 — pure VALU, no DS ops. On-device verified (R6/R9).
__device__ __forceinline__ float sum16(float x) {
    x += __int_as_float(__builtin_amdgcn_update_dpp(0, __float_as_int(x), 0xB1, 0xF, 0xF, true));
    x += __int_as_float(__builtin_amdgcn_update_dpp(0, __float_as_int(x), 0x4E, 0xF, 0xF, true));
    x += __int_as_float(__builtin_amdgcn_update_dpp(0, __float_as_int(x), 0x124, 0xF, 0xF, true));
    x += __int_as_float(__builtin_amdgcn_update_dpp(0, __float_as_int(x), 0x128, 0xF, 0xF, true));
    return x;
}

// ---------------- K1: fused logits+exp+row/col sums, 1 feat pass ----------------
// R9 structure + 4-deep prefetch ring: steady state keeps 4 independent 1KB
// wave-loads in flight (R9 had 1) -> 4x bytes in flight per CU. This is the
// single delta aimed at the ~2.6 TB/s latency-bound plateau.
__global__ __launch_bounds__(256, 4) void k_fused(const float* __restrict__ feat,
                                                  const float* __restrict__ Wq,
                                                  const float* __restrict__ bq,
                                                  float* __restrict__ rp,
                                                  float* __restrict__ cp) {
    __shared__ float4 lbuf[16][8][17];   // [u][ii][c4 pad 17]
    __shared__ float  zb[16][9];         // per-(u, ii) row-z contribution

    int t = threadIdx.x;
    int u = t >> 4, q = t & 15;
    int bi = blockIdx.x, bj = blockIdx.y;
    int i0 = bi * TS, j0 = bj * TS;

    const float4 wq = *reinterpret_cast<const float4*>(Wq + q * 4);
    const float bqv = bq[0];

    const float* fb = feat + ((size_t)i0 * LL + j0 + u) * CT + q * 4;
    const size_t istr = (size_t)LL * CT;
    float4 creg = make_float4(0.f, 0.f, 0.f, 0.f);
    float zc = 0.f;

    // prefetch ring, depth 4
    float4 fr0 = *reinterpret_cast<const float4*>(fb + 0 * istr);
    float4 fr1 = *reinterpret_cast<const float4*>(fb + 1 * istr);
    float4 fr2 = *reinterpret_cast<const float4*>(fb + 2 * istr);
    float4 fr3 = *reinterpret_cast<const float4*>(fb + 3 * istr);

    #pragma unroll
    for (int half = 0; half < 2; ++half) {
        #pragma unroll
        for (int ii = 0; ii < 8; ++ii) {
            const int idx = half * 8 + ii;
            float4 f;
            // static ring rotation (idx compile-time after unroll)
            if ((idx & 3) == 0) { f = fr0; if (idx + 4 < 16) fr0 = *reinterpret_cast<const float4*>(fb + (size_t)(idx + 4) * istr); }
            else if ((idx & 3) == 1) { f = fr1; if (idx + 4 < 16) fr1 = *reinterpret_cast<const float4*>(fb + (size_t)(idx + 4) * istr); }
            else if ((idx & 3) == 2) { f = fr2; if (idx + 4 < 16) fr2 = *reinterpret_cast<const float4*>(fb + (size_t)(idx + 4) * istr); }
            else                     { f = fr3; if (idx + 4 < 16) fr3 = *reinterpret_cast<const float4*>(fb + (size_t)(idx + 4) * istr); }

            float s = f.x * wq.x + f.y * wq.y + f.z * wq.z + f.w * wq.w;
            s = sum16(s);                    // DPP, pure VALU
            float e = __expf(s + bqv);

            float4 p;
            p.x = e * f.x; p.y = e * f.y; p.z = e * f.z; p.w = e * f.w;

            // col accumulation (register)
            creg.x += p.x; creg.y += p.y; creg.z += p.z; creg.w += p.w;
            zc += e;

            // row contribution: one LDS write (assignment, no RMW)
            lbuf[u][ii][q] = p;
            if (q == 0) zb[u][ii] = e;
        }
        __syncthreads();

        // fold row partials over the 16 u-columns
        if (t < 128) {
            int ii = t >> 4, c4 = t & 15;
            float4 a = make_float4(0.f, 0.f, 0.f, 0.f);
            #pragma unroll
            for (int uu = 0; uu < 16; ++uu) {
                const float4 v = lbuf[uu][ii][c4];
                a.x += v.x; a.y += v.y; a.z += v.z; a.w += v.w;
            }
            *reinterpret_cast<float4*>(rp + ((size_t)bj * LL + i0 + half * 8 + ii) * PCH
                                       + c4 * 4) = a;
        }
        if (t < 8) {
            float zz = 0.f;
            #pragma unroll
            for (int uu = 0; uu < 16; ++uu) zz += zb[uu][t];
            rp[((size_t)bj * LL + i0 + half * 8 + t) * PCH + 64] = zz;
        }
        __syncthreads();
    }

    // col partials out (registers -> global, once)
    size_t cpo = ((size_t)bi * LL + (j0 + u)) * PCH;
    *reinterpret_cast<float4*>(cp + cpo + q * 4) = creg;
    if (q == 0) cp[cpo + 64] = zc;
}

// ---------------- K2: inline combine + diag + LN + GEMM ----------------
// Combines the 48 strip-partials for its own 8 lines (both sides), then
// LN + (x @ W + b) [* sigma]. Replaces the separate k_combine dispatch.
__global__ __launch_bounds__(256) void k_final(const float* __restrict__ feat,
                                               const float* __restrict__ rp,
                                               const float* __restrict__ cp,
                                               const float* __restrict__ ln_g,
                                               const float* __restrict__ ln_b,
                                               const float* __restrict__ WU,
                                               const float* __restrict__ bU,
                                               const float* __restrict__ WV,
                                               const float* __restrict__ bV,
                                               const float* __restrict__ sigma,
                                               float* __restrict__ out) {
    __shared__ float cf2[2][8][68];   // [side][line][ch] normalized feats
    __shared__ float xbuf[8][KD];
    int t = threadIdx.x;
    int r0 = blockIdx.x * 8;
    int right = blockIdx.y;

    // combine: side = t>>7 (0 rows, 1 cols), r = (t>>4)&7, q = t&15
    {
        int side = t >> 7;
        int r = (t >> 4) & 7, q = t & 15;
        const float* base = side ? cp : rp;
        float4 acc = make_float4(0.f, 0.f, 0.f, 0.f);
        float z = 0.f;
        #pragma unroll 4
        for (int s = 0; s < NST; ++s) {
            const float* p = base + ((size_t)s * LL + r0 + r) * PCH;
            const float4 v = *reinterpret_cast<const float4*>(p + q * 4);
            acc.x += v.x; acc.y += v.y; acc.z += v.z; acc.w += v.w;
            z += p[64];
        }
        float inv = 1.0f / z;
        cf2[side][r][q * 4 + 0] = acc.x * inv;
        cf2[side][r][q * 4 + 1] = acc.y * inv;
        cf2[side][r][q * 4 + 2] = acc.z * inv;
        cf2[side][r][q * 4 + 3] = acc.w * inv;
    }
    __syncthreads();

    int wid = t >> 6, l = t & 63;
    for (int r = wid; r < 8; r += 4) {
        int i = r0 + r;
        float d  = feat[((size_t)i * LL + i) * CT + l];
        float rv = cf2[0][r][l];
        float cv = cf2[1][r][l];
        float sum = d + rv + cv;
        #pragma unroll
        for (int o = 32; o; o >>= 1) sum += __shfl_xor(sum, o);
        float mu = sum * (1.0f / 192.0f);
        float d0 = d - mu, d1 = rv - mu, d2 = cv - mu;
        float sq = d0 * d0 + d1 * d1 + d2 * d2;
        #pragma unroll
        for (int o = 32; o; o >>= 1) sq += __shfl_xor(sq, o);
        float rstd = rsqrtf(sq * (1.0f / 192.0f) + 1e-5f);
        float h0 = d0 * rstd, h1 = d1 * rstd, h2 = d2 * rstd;
        float a1 = right ? h2 : h1;
        float a2 = right ? h1 : h2;
        xbuf[r][l]       = h0 * ln_g[l]       + ln_b[l];
        xbuf[r][64 + l]  = a1 * ln_g[64 + l]  + ln_b[64 + l];
        xbuf[r][128 + l] = a2 * ln_g[128 + l] + ln_b[128 + l];
    }
    __syncthreads();

    const float* W    = right ? WV : WU;
    const float* bias = right ? bV : bU;
    int o = t * 4;
    float4 acc[8];
    #pragma unroll
    for (int r = 0; r < 8; ++r) acc[r] = make_float4(0.f, 0.f, 0.f, 0.f);

    for (int k = 0; k < KD; k += 4) {
        float4 xr[8];
        #pragma unroll
        for (int r = 0; r < 8; ++r)
            xr[r] = *reinterpret_cast<const float4*>(&xbuf[r][k]);
        #pragma unroll
        for (int kk = 0; kk < 4; ++kk) {
            float4 wv = *reinterpret_cast<const float4*>(W + (size_t)(k + kk) * OC + o);
            #pragma unroll
            for (int r = 0; r < 8; ++r) {
                float xv = (&xr[r].x)[kk];
                acc[r].x = fmaf(xv, wv.x, acc[r].x);
                acc[r].y = fmaf(xv, wv.y, acc[r].y);
                acc[r].z = fmaf(xv, wv.z, acc[r].z);
                acc[r].w = fmaf(xv, wv.w, acc[r].w);
            }
        }
    }

    float4 bb = *reinterpret_cast<const float4*>(bias + o);
    float sg = right ? 1.0f : sigma[o >> 7];
    float* obase = out + (right ? (size_t)LL * OC : 0);
    #pragma unroll
    for (int r = 0; r < 8; ++r) {
        float4 v;
        v.x = (acc[r].x + bb.x) * sg;
        v.y = (acc[r].y + bb.y) * sg;
        v.z = (acc[r].z + bb.z) * sg;
        v.w = (acc[r].w + bb.w) * sg;
        *reinterpret_cast<float4*>(obase + (size_t)(r0 + r) * OC + o) = v;
    }
}

extern "C" void kernel_launch(void* const* d_in, const int* in_sizes, int n_in,
                              void* d_out, int out_size, void* d_ws, size_t ws_size,
                              hipStream_t stream) {
    const float* feat  = (const float*)d_in[0];
    const float* Wq    = (const float*)d_in[1];
    const float* bq    = (const float*)d_in[2];
    const float* ln_g  = (const float*)d_in[3];
    const float* ln_b  = (const float*)d_in[4];
    const float* WU    = (const float*)d_in[5];
    const float* bU    = (const float*)d_in[6];
    const float* WV    = (const float*)d_in[7];
    const float* bV    = (const float*)d_in[8];
    const float* sigma = (const float*)d_in[9];
    float* out = (float*)d_out;

    float* ws = (float*)d_ws;
    float* rp = ws;                                  // NST*LL*PCH
    float* cp = rp + (size_t)NST * LL * PCH;         // NST*LL*PCH

    hipLaunchKernelGGL(k_fused, dim3(NST, NST), dim3(256), 0, stream,
                       feat, Wq, bq, rp, cp);
    hipLaunchKernelGGL(k_final, dim3(LL / 8, 2), dim3(256), 0, stream,
                       feat, rp, cp, ln_g, ln_b, WU, bU, WV, bV, sigma, out);
}

// Round 11
// 83.178 us; speedup vs baseline: 1.0190x; 1.0190x over previous
//
#include <hip/hip_runtime.h>
#include <math.h>

#define LL 768
#define CT 64
#define KD 192
#define OC 1024
#define TS 16
#define NST 48           // 768/16 tiles per dim
#define PCH 68           // partial line: 64 ch + z at [64], padded to 68

// 16-lane-group sum via DPP: quad_perm(xor1), quad_perm(xor2), row_ror:4,
// row_ror:8 — pure VALU, no DS ops. On-device verified (R6/R9).
__device__ __forceinline__ float sum16(float x) {
    x += __int_as_float(__builtin_amdgcn_update_dpp(0, __float_as_int(x), 0xB1, 0xF, 0xF, true));
    x += __int_as_float(__builtin_amdgcn_update_dpp(0, __float_as_int(x), 0x4E, 0xF, 0xF, true));
    x += __int_as_float(__builtin_amdgcn_update_dpp(0, __float_as_int(x), 0x124, 0xF, 0xF, true));
    x += __int_as_float(__builtin_amdgcn_update_dpp(0, __float_as_int(x), 0x128, 0xF, 0xF, true));
    return x;
}

// ---------------- K1: fused logits+exp+row/col sums, 1 feat pass ----------------
// R9 structure with ONE change: row-fold chunk 8 -> 4, halving lbuf LDS
// (35.4KB -> 17.7KB). Occupancy cap moves 4 -> 6 blocks/CU (24 waves/CU),
// 1.5x bytes in flight. Prefetch (2-deep fnext), DPP dot, all else identical.
__global__ __launch_bounds__(256, 6) void k_fused(const float* __restrict__ feat,
                                                  const float* __restrict__ Wq,
                                                  const float* __restrict__ bq,
                                                  float* __restrict__ rp,
                                                  float* __restrict__ cp) {
    __shared__ float4 lbuf[16][4][17];   // [u][ii][c4 pad 17]  (17.4 KB)
    __shared__ float  zb[16][5];         // per-(u, ii) row-z contribution

    int t = threadIdx.x;
    int u = t >> 4, q = t & 15;
    int bi = blockIdx.x, bj = blockIdx.y;
    int i0 = bi * TS, j0 = bj * TS;

    const float4 wq = *reinterpret_cast<const float4*>(Wq + q * 4);
    const float bqv = bq[0];

    const float* fb = feat + ((size_t)i0 * LL + j0 + u) * CT + q * 4;
    const size_t istr = (size_t)LL * CT;
    float4 creg = make_float4(0.f, 0.f, 0.f, 0.f);
    float zc = 0.f;

    float4 fnext = *reinterpret_cast<const float4*>(fb);

    for (int chunk = 0; chunk < 4; ++chunk) {
        #pragma unroll
        for (int ii = 0; ii < 4; ++ii) {
            const int idx = chunk * 4 + ii;
            const float4 f = fnext;
            if (idx < 15)
                fnext = *reinterpret_cast<const float4*>(fb + (size_t)(idx + 1) * istr);

            float s = f.x * wq.x + f.y * wq.y + f.z * wq.z + f.w * wq.w;
            s = sum16(s);                    // DPP, pure VALU
            float e = __expf(s + bqv);

            float4 p;
            p.x = e * f.x; p.y = e * f.y; p.z = e * f.z; p.w = e * f.w;

            // col accumulation (register)
            creg.x += p.x; creg.y += p.y; creg.z += p.z; creg.w += p.w;
            zc += e;

            // row contribution: one LDS write (assignment, no RMW)
            lbuf[u][ii][q] = p;
            if (q == 0) zb[u][ii] = e;
        }
        __syncthreads();

        // fold row partials over the 16 u-columns (4 lines per chunk)
        if (t < 64) {
            int ii = t >> 4, c4 = t & 15;
            float4 a = make_float4(0.f, 0.f, 0.f, 0.f);
            #pragma unroll
            for (int uu = 0; uu < 16; ++uu) {
                const float4 v = lbuf[uu][ii][c4];
                a.x += v.x; a.y += v.y; a.z += v.z; a.w += v.w;
            }
            *reinterpret_cast<float4*>(rp + ((size_t)bj * LL + i0 + chunk * 4 + ii) * PCH
                                       + c4 * 4) = a;
        }
        if (t < 4) {
            float zz = 0.f;
            #pragma unroll
            for (int uu = 0; uu < 16; ++uu) zz += zb[uu][t];
            rp[((size_t)bj * LL + i0 + chunk * 4 + t) * PCH + 64] = zz;
        }
        __syncthreads();
    }

    // col partials out (registers -> global, once)
    size_t cpo = ((size_t)bi * LL + (j0 + u)) * PCH;
    *reinterpret_cast<float4*>(cp + cpo + q * 4) = creg;
    if (q == 0) cp[cpo + 64] = zc;
}

// ---------------- K2: fold 48 strip-partials, divide by z -> rcfeat ----------
__global__ __launch_bounds__(256) void k_combine(const float* __restrict__ rp,
                                                 const float* __restrict__ cp,
                                                 float* __restrict__ rcfeat) {
    int t = threadIdx.x;
    int r = t >> 4, q = t & 15;
    int L0 = blockIdx.x * 16;
    int side = blockIdx.y;
    const float* base = side ? cp : rp;

    float4 acc = make_float4(0.f, 0.f, 0.f, 0.f);
    float z = 0.f;
    #pragma unroll 4
    for (int s = 0; s < NST; ++s) {
        const float* p = base + ((size_t)s * LL + L0 + r) * PCH;
        const float4 v = *reinterpret_cast<const float4*>(p + q * 4);
        acc.x += v.x; acc.y += v.y; acc.z += v.z; acc.w += v.w;
        z += p[64];
    }
    float inv = 1.0f / z;
    acc.x *= inv; acc.y *= inv; acc.z *= inv; acc.w *= inv;
    *reinterpret_cast<float4*>(rcfeat + (size_t)side * LL * CT
                               + (L0 + r) * CT + q * 4) = acc;
}

// ---------------- K3: diag gather + LN + (x @ W + b) [*sigma] ----------------
__global__ __launch_bounds__(256) void k_final(const float* __restrict__ feat,
                                               const float* __restrict__ rcfeat,
                                               const float* __restrict__ ln_g,
                                               const float* __restrict__ ln_b,
                                               const float* __restrict__ WU,
                                               const float* __restrict__ bU,
                                               const float* __restrict__ WV,
                                               const float* __restrict__ bV,
                                               const float* __restrict__ sigma,
                                               float* __restrict__ out) {
    __shared__ float xbuf[8][KD];
    int t = threadIdx.x;
    int wid = t >> 6, l = t & 63;
    int r0 = blockIdx.x * 8;
    int right = blockIdx.y;
    const float* rfeat = rcfeat;
    const float* cfeat = rcfeat + LL * CT;

    for (int r = wid; r < 8; r += 4) {
        int i = r0 + r;
        float d  = feat[((size_t)i * LL + i) * CT + l];
        float rv = rfeat[(size_t)i * CT + l];
        float cv = cfeat[(size_t)i * CT + l];
        float sum = d + rv + cv;
        #pragma unroll
        for (int o = 32; o; o >>= 1) sum += __shfl_xor(sum, o);
        float mu = sum * (1.0f / 192.0f);
        float d0 = d - mu, d1 = rv - mu, d2 = cv - mu;
        float sq = d0 * d0 + d1 * d1 + d2 * d2;
        #pragma unroll
        for (int o = 32; o; o >>= 1) sq += __shfl_xor(sq, o);
        float rstd = rsqrtf(sq * (1.0f / 192.0f) + 1e-5f);
        float h0 = d0 * rstd, h1 = d1 * rstd, h2 = d2 * rstd;
        float a1 = right ? h2 : h1;
        float a2 = right ? h1 : h2;
        xbuf[r][l]       = h0 * ln_g[l]       + ln_b[l];
        xbuf[r][64 + l]  = a1 * ln_g[64 + l]  + ln_b[64 + l];
        xbuf[r][128 + l] = a2 * ln_g[128 + l] + ln_b[128 + l];
    }
    __syncthreads();

    const float* W    = right ? WV : WU;
    const float* bias = right ? bV : bU;
    int o = t * 4;
    float4 acc[8];
    #pragma unroll
    for (int r = 0; r < 8; ++r) acc[r] = make_float4(0.f, 0.f, 0.f, 0.f);

    for (int k = 0; k < KD; k += 4) {
        float4 xr[8];
        #pragma unroll
        for (int r = 0; r < 8; ++r)
            xr[r] = *reinterpret_cast<const float4*>(&xbuf[r][k]);
        #pragma unroll
        for (int kk = 0; kk < 4; ++kk) {
            float4 wv = *reinterpret_cast<const float4*>(W + (size_t)(k + kk) * OC + o);
            #pragma unroll
            for (int r = 0; r < 8; ++r) {
                float xv = (&xr[r].x)[kk];
                acc[r].x = fmaf(xv, wv.x, acc[r].x);
                acc[r].y = fmaf(xv, wv.y, acc[r].y);
                acc[r].z = fmaf(xv, wv.z, acc[r].z);
                acc[r].w = fmaf(xv, wv.w, acc[r].w);
            }
        }
    }

    float4 bb = *reinterpret_cast<const float4*>(bias + o);
    float sg = right ? 1.0f : sigma[o >> 7];
    float* obase = out + (right ? (size_t)LL * OC : 0);
    #pragma unroll
    for (int r = 0; r < 8; ++r) {
        float4 v;
        v.x = (acc[r].x + bb.x) * sg;
        v.y = (acc[r].y + bb.y) * sg;
        v.z = (acc[r].z + bb.z) * sg;
        v.w = (acc[r].w + bb.w) * sg;
        *reinterpret_cast<float4*>(obase + (size_t)(r0 + r) * OC + o) = v;
    }
}

extern "C" void kernel_launch(void* const* d_in, const int* in_sizes, int n_in,
                              void* d_out, int out_size, void* d_ws, size_t ws_size,
                              hipStream_t stream) {
    const float* feat  = (const float*)d_in[0];
    const float* Wq    = (const float*)d_in[1];
    const float* bq    = (const float*)d_in[2];
    const float* ln_g  = (const float*)d_in[3];
    const float* ln_b  = (const float*)d_in[4];
    const float* WU    = (const float*)d_in[5];
    const float* bU    = (const float*)d_in[6];
    const float* WV    = (const float*)d_in[7];
    const float* bV    = (const float*)d_in[8];
    const float* sigma = (const float*)d_in[9];
    float* out = (float*)d_out;

    float* ws     = (float*)d_ws;
    float* rp     = ws;                                  // NST*LL*PCH
    float* cp     = rp + (size_t)NST * LL * PCH;         // NST*LL*PCH
    float* rcfeat = cp + (size_t)NST * LL * PCH;         // 2*LL*CT

    hipLaunchKernelGGL(k_fused, dim3(NST, NST), dim3(256), 0, stream,
                       feat, Wq, bq, rp, cp);
    hipLaunchKernelGGL(k_combine, dim3(NST, 2), dim3(256), 0, stream,
                       rp, cp, rcfeat);
    hipLaunchKernelGGL(k_final, dim3(LL / 8, 2), dim3(256), 0, stream,
                       feat, rcfeat, ln_g, ln_b, WU, bU, WV, bV, sigma, out);
}

// Round 12
// 75.797 us; speedup vs baseline: 1.1182x; 1.0974x over previous
//
#include <hip/hip_runtime.h>
#include <math.h>

#define LL 768
#define CT 64
#define KD 192
#define OC 1024
#define TS 16
#define NST 48           // 768/16 tiles per dim
#define PCH 68           // partial line: 64 ch + z at [64], padded to 68

// 16-lane-group sum via DPP: quad_perm(xor1), quad_perm(xor2), row_ror:4,
// row_ror:8 — pure VALU, no DS ops. On-device verified (R6/R9).
__device__ __forceinline__ float sum16(float x) {
    x += __int_as_float(__builtin_amdgcn_update_dpp(0, __float_as_int(x), 0xB1, 0xF, 0xF, true));
    x += __int_as_float(__builtin_amdgcn_update_dpp(0, __float_as_int(x), 0x4E, 0xF, 0xF, true));
    x += __int_as_float(__builtin_amdgcn_update_dpp(0, __float_as_int(x), 0x124, 0xF, 0xF, true));
    x += __int_as_float(__builtin_amdgcn_update_dpp(0, __float_as_int(x), 0x128, 0xF, 0xF, true));
    return x;
}

// ---------------- K1: fused logits+exp+row/col sums, 1 feat pass ----------------
// EXACT R9 kernel body. Single delta: grid mapping swapped — bj = blockIdx.x
// (fast dispatch dim), bi = blockIdx.y. Co-resident blocks now cover a
// CONTIGUOUS i-band (~65MB sliding window) instead of scattered 4KB chunks
// across the whole 151MB buffer -> DRAM page / L3-window locality.
__global__ __launch_bounds__(256, 6) void k_fused(const float* __restrict__ feat,
                                                  const float* __restrict__ Wq,
                                                  const float* __restrict__ bq,
                                                  float* __restrict__ rp,
                                                  float* __restrict__ cp) {
    __shared__ float4 lbuf[16][8][17];   // [u][ii][c4 pad 17]
    __shared__ float  zb[16][9];         // per-(u, ii) row-z contribution

    int t = threadIdx.x;
    int u = t >> 4, q = t & 15;
    int bj = blockIdx.x, bi = blockIdx.y;   // <-- the only change vs R9
    int i0 = bi * TS, j0 = bj * TS;

    const float4 wq = *reinterpret_cast<const float4*>(Wq + q * 4);
    const float bqv = bq[0];

    const float* fb = feat + ((size_t)i0 * LL + j0 + u) * CT + q * 4;
    const size_t istr = (size_t)LL * CT;
    float4 creg = make_float4(0.f, 0.f, 0.f, 0.f);
    float zc = 0.f;

    float4 fnext = *reinterpret_cast<const float4*>(fb);

    #pragma unroll 2
    for (int half = 0; half < 2; ++half) {
        #pragma unroll
        for (int ii = 0; ii < 8; ++ii) {
            const int idx = half * 8 + ii;
            const float4 f = fnext;
            if (idx < 15)
                fnext = *reinterpret_cast<const float4*>(fb + (size_t)(idx + 1) * istr);

            float s = f.x * wq.x + f.y * wq.y + f.z * wq.z + f.w * wq.w;
            s = sum16(s);                    // DPP, pure VALU
            float e = __expf(s + bqv);

            float4 p;
            p.x = e * f.x; p.y = e * f.y; p.z = e * f.z; p.w = e * f.w;

            // col accumulation (register)
            creg.x += p.x; creg.y += p.y; creg.z += p.z; creg.w += p.w;
            zc += e;

            // row contribution: one LDS write (assignment, no RMW)
            lbuf[u][ii][q] = p;
            if (q == 0) zb[u][ii] = e;
        }
        __syncthreads();

        // fold row partials over the 16 u-columns
        if (t < 128) {
            int ii = t >> 4, c4 = t & 15;
            float4 a = make_float4(0.f, 0.f, 0.f, 0.f);
            #pragma unroll
            for (int uu = 0; uu < 16; ++uu) {
                const float4 v = lbuf[uu][ii][c4];
                a.x += v.x; a.y += v.y; a.z += v.z; a.w += v.w;
            }
            *reinterpret_cast<float4*>(rp + ((size_t)bj * LL + i0 + half * 8 + ii) * PCH
                                       + c4 * 4) = a;
        }
        if (t < 8) {
            float zz = 0.f;
            #pragma unroll
            for (int uu = 0; uu < 16; ++uu) zz += zb[uu][t];
            rp[((size_t)bj * LL + i0 + half * 8 + t) * PCH + 64] = zz;
        }
        __syncthreads();
    }

    // col partials out (registers -> global, once)
    size_t cpo = ((size_t)bi * LL + (j0 + u)) * PCH;
    *reinterpret_cast<float4*>(cp + cpo + q * 4) = creg;
    if (q == 0) cp[cpo + 64] = zc;
}

// ---------------- K2: fold 48 strip-partials, divide by z -> rcfeat ----------
__global__ __launch_bounds__(256) void k_combine(const float* __restrict__ rp,
                                                 const float* __restrict__ cp,
                                                 float* __restrict__ rcfeat) {
    int t = threadIdx.x;
    int r = t >> 4, q = t & 15;
    int L0 = blockIdx.x * 16;
    int side = blockIdx.y;
    const float* base = side ? cp : rp;

    float4 acc = make_float4(0.f, 0.f, 0.f, 0.f);
    float z = 0.f;
    #pragma unroll 4
    for (int s = 0; s < NST; ++s) {
        const float* p = base + ((size_t)s * LL + L0 + r) * PCH;
        const float4 v = *reinterpret_cast<const float4*>(p + q * 4);
        acc.x += v.x; acc.y += v.y; acc.z += v.z; acc.w += v.w;
        z += p[64];
    }
    float inv = 1.0f / z;
    acc.x *= inv; acc.y *= inv; acc.z *= inv; acc.w *= inv;
    *reinterpret_cast<float4*>(rcfeat + (size_t)side * LL * CT
                               + (L0 + r) * CT + q * 4) = acc;
}

// ---------------- K3: diag gather + LN + (x @ W + b) [*sigma] ----------------
__global__ __launch_bounds__(256) void k_final(const float* __restrict__ feat,
                                               const float* __restrict__ rcfeat,
                                               const float* __restrict__ ln_g,
                                               const float* __restrict__ ln_b,
                                               const float* __restrict__ WU,
                                               const float* __restrict__ bU,
                                               const float* __restrict__ WV,
                                               const float* __restrict__ bV,
                                               const float* __restrict__ sigma,
                                               float* __restrict__ out) {
    __shared__ float xbuf[8][KD];
    int t = threadIdx.x;
    int wid = t >> 6, l = t & 63;
    int r0 = blockIdx.x * 8;
    int right = blockIdx.y;
    const float* rfeat = rcfeat;
    const float* cfeat = rcfeat + LL * CT;

    for (int r = wid; r < 8; r += 4) {
        int i = r0 + r;
        float d  = feat[((size_t)i * LL + i) * CT + l];
        float rv = rfeat[(size_t)i * CT + l];
        float cv = cfeat[(size_t)i * CT + l];
        float sum = d + rv + cv;
        #pragma unroll
        for (int o = 32; o; o >>= 1) sum += __shfl_xor(sum, o);
        float mu = sum * (1.0f / 192.0f);
        float d0 = d - mu, d1 = rv - mu, d2 = cv - mu;
        float sq = d0 * d0 + d1 * d1 + d2 * d2;
        #pragma unroll
        for (int o = 32; o; o >>= 1) sq += __shfl_xor(sq, o);
        float rstd = rsqrtf(sq * (1.0f / 192.0f) + 1e-5f);
        float h0 = d0 * rstd, h1 = d1 * rstd, h2 = d2 * rstd;
        float a1 = right ? h2 : h1;
        float a2 = right ? h1 : h2;
        xbuf[r][l]       = h0 * ln_g[l]       + ln_b[l];
        xbuf[r][64 + l]  = a1 * ln_g[64 + l]  + ln_b[64 + l];
        xbuf[r][128 + l] = a2 * ln_g[128 + l] + ln_b[128 + l];
    }
    __syncthreads();

    const float* W    = right ? WV : WU;
    const float* bias = right ? bV : bU;
    int o = t * 4;
    float4 acc[8];
    #pragma unroll
    for (int r = 0; r < 8; ++r) acc[r] = make_float4(0.f, 0.f, 0.f, 0.f);

    for (int k = 0; k < KD; k += 4) {
        float4 xr[8];
        #pragma unroll
        for (int r = 0; r < 8; ++r)
            xr[r] = *reinterpret_cast<const float4*>(&xbuf[r][k]);
        #pragma unroll
        for (int kk = 0; kk < 4; ++kk) {
            float4 wv = *reinterpret_cast<const float4*>(W + (size_t)(k + kk) * OC + o);
            #pragma unroll
            for (int r = 0; r < 8; ++r) {
                float xv = (&xr[r].x)[kk];
                acc[r].x = fmaf(xv, wv.x, acc[r].x);
                acc[r].y = fmaf(xv, wv.y, acc[r].y);
                acc[r].z = fmaf(xv, wv.z, acc[r].z);
                acc[r].w = fmaf(xv, wv.w, acc[r].w);
            }
        }
    }

    float4 bb = *reinterpret_cast<const float4*>(bias + o);
    float sg = right ? 1.0f : sigma[o >> 7];
    float* obase = out + (right ? (size_t)LL * OC : 0);
    #pragma unroll
    for (int r = 0; r < 8; ++r) {
        float4 v;
        v.x = (acc[r].x + bb.x) * sg;
        v.y = (acc[r].y + bb.y) * sg;
        v.z = (acc[r].z + bb.z) * sg;
        v.w = (acc[r].w + bb.w) * sg;
        *reinterpret_cast<float4*>(obase + (size_t)(r0 + r) * OC + o) = v;
    }
}

extern "C" void kernel_launch(void* const* d_in, const int* in_sizes, int n_in,
                              void* d_out, int out_size, void* d_ws, size_t ws_size,
                              hipStream_t stream) {
    const float* feat  = (const float*)d_in[0];
    const float* Wq    = (const float*)d_in[1];
    const float* bq    = (const float*)d_in[2];
    const float* ln_g  = (const float*)d_in[3];
    const float* ln_b  = (const float*)d_in[4];
    const float* WU    = (const float*)d_in[5];
    const float* bU    = (const float*)d_in[6];
    const float* WV    = (const float*)d_in[7];
    const float* bV    = (const float*)d_in[8];
    const float* sigma = (const float*)d_in[9];
    float* out = (float*)d_out;

    float* ws     = (float*)d_ws;
    float* rp     = ws;                                  // NST*LL*PCH
    float* cp     = rp + (size_t)NST * LL * PCH;         // NST*LL*PCH
    float* rcfeat = cp + (size_t)NST * LL * PCH;         // 2*LL*CT

    hipLaunchKernelGGL(k_fused, dim3(NST, NST), dim3(256), 0, stream,
                       feat, Wq, bq, rp, cp);
    hipLaunchKernelGGL(k_combine, dim3(NST, 2), dim3(256), 0, stream,
                       rp, cp, rcfeat);
    hipLaunchKernelGGL(k_final, dim3(LL / 8, 2), dim3(256), 0, stream,
                       feat, rcfeat, ln_g, ln_b, WU, bU, WV, bV, sigma, out);
}

// Round 13
// 61.701 us; speedup vs baseline: 1.3737x; 1.2285x over previous
//
#include <hip/hip_runtime.h>
#include <math.h>

#define LL 768
#define CT 64
#define KD 192
#define OC 1024
#define TS 16
#define NST 48           // 768/16 tiles per dim
#define PCH 68           // partial line: 64 ch + z at [64], padded to 68

// 16-lane-group sum via DPP: quad_perm(xor1), quad_perm(xor2), row_ror:4,
// row_ror:8 — pure VALU, no DS ops. On-device verified (R6/R9).
__device__ __forceinline__ float sum16(float x) {
    x += __int_as_float(__builtin_amdgcn_update_dpp(0, __float_as_int(x), 0xB1, 0xF, 0xF, true));
    x += __int_as_float(__builtin_amdgcn_update_dpp(0, __float_as_int(x), 0x4E, 0xF, 0xF, true));
    x += __int_as_float(__builtin_amdgcn_update_dpp(0, __float_as_int(x), 0x124, 0xF, 0xF, true));
    x += __int_as_float(__builtin_amdgcn_update_dpp(0, __float_as_int(x), 0x128, 0xF, 0xF, true));
    return x;
}

// ---------------- K1: fused logits+exp+row/col sums, 1 feat pass ----------------
// EXACT R12 body; only the rp/cp write layout is transposed to line-major
// ([line][strip][PCH]) so the tail kernels read contiguously.
__global__ __launch_bounds__(256, 6) void k_fused(const float* __restrict__ feat,
                                                  const float* __restrict__ Wq,
                                                  const float* __restrict__ bq,
                                                  float* __restrict__ rp,
                                                  float* __restrict__ cp) {
    __shared__ float4 lbuf[16][8][17];   // [u][ii][c4 pad 17]
    __shared__ float  zb[16][9];         // per-(u, ii) row-z contribution

    int t = threadIdx.x;
    int u = t >> 4, q = t & 15;
    int bj = blockIdx.x, bi = blockIdx.y;   // bj fast (R12 mapping, neutral)
    int i0 = bi * TS, j0 = bj * TS;

    const float4 wq = *reinterpret_cast<const float4*>(Wq + q * 4);
    const float bqv = bq[0];

    const float* fb = feat + ((size_t)i0 * LL + j0 + u) * CT + q * 4;
    const size_t istr = (size_t)LL * CT;
    float4 creg = make_float4(0.f, 0.f, 0.f, 0.f);
    float zc = 0.f;

    float4 fnext = *reinterpret_cast<const float4*>(fb);

    #pragma unroll 2
    for (int half = 0; half < 2; ++half) {
        #pragma unroll
        for (int ii = 0; ii < 8; ++ii) {
            const int idx = half * 8 + ii;
            const float4 f = fnext;
            if (idx < 15)
                fnext = *reinterpret_cast<const float4*>(fb + (size_t)(idx + 1) * istr);

            float s = f.x * wq.x + f.y * wq.y + f.z * wq.z + f.w * wq.w;
            s = sum16(s);                    // DPP, pure VALU
            float e = __expf(s + bqv);

            float4 p;
            p.x = e * f.x; p.y = e * f.y; p.z = e * f.z; p.w = e * f.w;

            // col accumulation (register)
            creg.x += p.x; creg.y += p.y; creg.z += p.z; creg.w += p.w;
            zc += e;

            // row contribution: one LDS write (assignment, no RMW)
            lbuf[u][ii][q] = p;
            if (q == 0) zb[u][ii] = e;
        }
        __syncthreads();

        // fold row partials over the 16 u-columns -> rp[line][strip=bj][*]
        if (t < 128) {
            int ii = t >> 4, c4 = t & 15;
            float4 a = make_float4(0.f, 0.f, 0.f, 0.f);
            #pragma unroll
            for (int uu = 0; uu < 16; ++uu) {
                const float4 v = lbuf[uu][ii][c4];
                a.x += v.x; a.y += v.y; a.z += v.z; a.w += v.w;
            }
            *reinterpret_cast<float4*>(rp + ((size_t)(i0 + half * 8 + ii) * NST + bj) * PCH
                                       + c4 * 4) = a;
        }
        if (t < 8) {
            float zz = 0.f;
            #pragma unroll
            for (int uu = 0; uu < 16; ++uu) zz += zb[uu][t];
            rp[((size_t)(i0 + half * 8 + t) * NST + bj) * PCH + 64] = zz;
        }
        __syncthreads();
    }

    // col partials out -> cp[line=j][strip=bi][*]
    size_t cpo = ((size_t)(j0 + u) * NST + bi) * PCH;
    *reinterpret_cast<float4*>(cp + cpo + q * 4) = creg;
    if (q == 0) cp[cpo + 64] = zc;
}

// ---------------- K2: fold 48 strip-partials (line-major), /z -> rcfeat -------
// Line-major layout: per line the 48 partials are 48x272B quasi-contiguous.
__global__ __launch_bounds__(256) void k_combine(const float* __restrict__ rp,
                                                 const float* __restrict__ cp,
                                                 float* __restrict__ rcfeat) {
    int t = threadIdx.x;
    int r = t >> 4, q = t & 15;
    int L = blockIdx.x * 16 + r;
    int side = blockIdx.y;
    const float* base = (side ? cp : rp) + (size_t)L * NST * PCH;

    float4 acc = make_float4(0.f, 0.f, 0.f, 0.f);
    float z = 0.f;
    #pragma unroll 4
    for (int s = 0; s < NST; ++s) {
        const float4 v = *reinterpret_cast<const float4*>(base + s * PCH + q * 4);
        acc.x += v.x; acc.y += v.y; acc.z += v.z; acc.w += v.w;
        z += base[s * PCH + 64];             // broadcast within 16-lane group
    }
    float inv = 1.0f / z;
    acc.x *= inv; acc.y *= inv; acc.z *= inv; acc.w *= inv;
    *reinterpret_cast<float4*>(rcfeat + (size_t)side * LL * CT
                               + (size_t)L * CT + q * 4) = acc;
}

// ---------------- K3: diag gather + LN + (x @ W + b) [*sigma] ----------------
// grid (96, 2, 2): blockIdx.z splits OC in half -> 384 blocks (1.5/CU),
// per-thread FMA halved; W traffic unchanged (L2-resident).
__global__ __launch_bounds__(256) void k_final(const float* __restrict__ feat,
                                               const float* __restrict__ rcfeat,
                                               const float* __restrict__ ln_g,
                                               const float* __restrict__ ln_b,
                                               const float* __restrict__ WU,
                                               const float* __restrict__ bU,
                                               const float* __restrict__ WV,
                                               const float* __restrict__ bV,
                                               const float* __restrict__ sigma,
                                               float* __restrict__ out) {
    __shared__ float xbuf[8][KD];
    int t = threadIdx.x;
    int wid = t >> 6, l = t & 63;
    int r0 = blockIdx.x * 8;
    int right = blockIdx.y;
    const float* rfeat = rcfeat;
    const float* cfeat = rcfeat + LL * CT;

    for (int r = wid; r < 8; r += 4) {
        int i = r0 + r;
        float d  = feat[((size_t)i * LL + i) * CT + l];
        float rv = rfeat[(size_t)i * CT + l];
        float cv = cfeat[(size_t)i * CT + l];
        float sum = d + rv + cv;
        #pragma unroll
        for (int o = 32; o; o >>= 1) sum += __shfl_xor(sum, o);
        float mu = sum * (1.0f / 192.0f);
        float d0 = d - mu, d1 = rv - mu, d2 = cv - mu;
        float sq = d0 * d0 + d1 * d1 + d2 * d2;
        #pragma unroll
        for (int o = 32; o; o >>= 1) sq += __shfl_xor(sq, o);
        float rstd = rsqrtf(sq * (1.0f / 192.0f) + 1e-5f);
        float h0 = d0 * rstd, h1 = d1 * rstd, h2 = d2 * rstd;
        float a1 = right ? h2 : h1;
        float a2 = right ? h1 : h2;
        xbuf[r][l]       = h0 * ln_g[l]       + ln_b[l];
        xbuf[r][64 + l]  = a1 * ln_g[64 + l]  + ln_b[64 + l];
        xbuf[r][128 + l] = a2 * ln_g[128 + l] + ln_b[128 + l];
    }
    __syncthreads();

    const float* W    = right ? WV : WU;
    const float* bias = right ? bV : bU;
    int o = blockIdx.z * 512 + t * 2;       // 2 columns per thread
    float2 acc[8];
    #pragma unroll
    for (int r = 0; r < 8; ++r) acc[r] = make_float2(0.f, 0.f);

    for (int k = 0; k < KD; k += 4) {
        float4 xr[8];
        #pragma unroll
        for (int r = 0; r < 8; ++r)
            xr[r] = *reinterpret_cast<const float4*>(&xbuf[r][k]);
        #pragma unroll
        for (int kk = 0; kk < 4; ++kk) {
            const float2 wv = *reinterpret_cast<const float2*>(W + (size_t)(k + kk) * OC + o);
            #pragma unroll
            for (int r = 0; r < 8; ++r) {
                float xv = (&xr[r].x)[kk];
                acc[r].x = fmaf(xv, wv.x, acc[r].x);
                acc[r].y = fmaf(xv, wv.y, acc[r].y);
            }
        }
    }

    const float2 bb = *reinterpret_cast<const float2*>(bias + o);
    float sg = right ? 1.0f : sigma[o >> 7];
    float* obase = out + (right ? (size_t)LL * OC : 0);
    #pragma unroll
    for (int r = 0; r < 8; ++r) {
        float2 v;
        v.x = (acc[r].x + bb.x) * sg;
        v.y = (acc[r].y + bb.y) * sg;
        *reinterpret_cast<float2*>(obase + (size_t)(r0 + r) * OC + o) = v;
    }
}

extern "C" void kernel_launch(void* const* d_in, const int* in_sizes, int n_in,
                              void* d_out, int out_size, void* d_ws, size_t ws_size,
                              hipStream_t stream) {
    const float* feat  = (const float*)d_in[0];
    const float* Wq    = (const float*)d_in[1];
    const float* bq    = (const float*)d_in[2];
    const float* ln_g  = (const float*)d_in[3];
    const float* ln_b  = (const float*)d_in[4];
    const float* WU    = (const float*)d_in[5];
    const float* bU    = (const float*)d_in[6];
    const float* WV    = (const float*)d_in[7];
    const float* bV    = (const float*)d_in[8];
    const float* sigma = (const float*)d_in[9];
    float* out = (float*)d_out;

    float* ws     = (float*)d_ws;
    float* rp     = ws;                                  // LL*NST*PCH
    float* cp     = rp + (size_t)LL * NST * PCH;         // LL*NST*PCH
    float* rcfeat = cp + (size_t)LL * NST * PCH;         // 2*LL*CT

    hipLaunchKernelGGL(k_fused, dim3(NST, NST), dim3(256), 0, stream,
                       feat, Wq, bq, rp, cp);
    hipLaunchKernelGGL(k_combine, dim3(LL / 16, 2), dim3(256), 0, stream,
                       rp, cp, rcfeat);
    hipLaunchKernelGGL(k_final, dim3(LL / 8, 2, 2), dim3(256), 0, stream,
                       feat, rcfeat, ln_g, ln_b, WU, bU, WV, bV, sigma, out);
}